// Round 3
// baseline (362.491 us; speedup 1.0000x reference)
//
#include <hip/hip_runtime.h>

// Trilinear feature interpolation:
//   out[n,f] = sum_{k=0..7} clamp(coeffs[n,k],0,1) * features[corner_idx[n,k], f]
// N = 1e6 queries, V = 1e6 rows, F = 32 features.
//
// Mapping: 256-thread block = 32 queries. Thread t -> (query q = t/8, feature
// group g = t%8, 4 floats). Each (query,corner) gather = one 128 B txn spread
// across 8 lanes.
//
// Round 3 change: rounds 1-2 compiled to identical code (VGPR=28) — the
// scheduler sank each gather to just before its use (MLP~2). Here we pin the
// schedule with __builtin_amdgcn_sched_barrier(0) so all 8 global_load_dwordx4
// issue before any consumer (MLP=8/wave). This is the latency-vs-MSHR
// hypothesis test: latency-bound -> ~2x faster; MSHR-bound -> neutral.

constexpr int F = 32;
constexpr int QUERIES_PER_BLOCK = 32;   // 32 queries * 8 threads = 256 threads

__global__ __launch_bounds__(256) void SPC_85469849190654_kernel(
    const float* __restrict__ coeffs,      // [N,8]
    const int*   __restrict__ corner_idx,  // [N,8]
    const float* __restrict__ features,    // [V,F]
    float*       __restrict__ out,         // [N,F]
    int N)
{
    __shared__ int   s_idx[256];
    __shared__ float s_c[256];

    const int t  = threadIdx.x;
    const int q0 = blockIdx.x * QUERIES_PER_BLOCK;

    const long long load_pos = (long long)q0 * 8 + t;
    if (load_pos < (long long)N * 8) {
        s_idx[t] = corner_idx[load_pos];
        s_c[t]   = coeffs[load_pos];
    } else {
        s_idx[t] = 0;
        s_c[t]   = 0.0f;
    }
    __syncthreads();

    const int q_local = t >> 3;      // 0..31
    const int g       = t & 7;       // 0..7 (feature group of 4)
    const int n       = q0 + q_local;
    if (n >= N) return;

    const int    qbase = q_local << 3;
    const float* fb    = features + (g << 2);

    // Resolve all 8 addresses (LDS reads) first.
    const float* p0 = fb + (size_t)s_idx[qbase + 0] * F;
    const float* p1 = fb + (size_t)s_idx[qbase + 1] * F;
    const float* p2 = fb + (size_t)s_idx[qbase + 2] * F;
    const float* p3 = fb + (size_t)s_idx[qbase + 3] * F;
    const float* p4 = fb + (size_t)s_idx[qbase + 4] * F;
    const float* p5 = fb + (size_t)s_idx[qbase + 5] * F;
    const float* p6 = fb + (size_t)s_idx[qbase + 6] * F;
    const float* p7 = fb + (size_t)s_idx[qbase + 7] * F;

    __builtin_amdgcn_sched_barrier(0);   // fence: addresses done

    // Phase 1: issue all 8 gathers back-to-back — nothing may interleave.
    const float4 f0 = *reinterpret_cast<const float4*>(p0);
    const float4 f1 = *reinterpret_cast<const float4*>(p1);
    const float4 f2 = *reinterpret_cast<const float4*>(p2);
    const float4 f3 = *reinterpret_cast<const float4*>(p3);
    const float4 f4 = *reinterpret_cast<const float4*>(p4);
    const float4 f5 = *reinterpret_cast<const float4*>(p5);
    const float4 f6 = *reinterpret_cast<const float4*>(p6);
    const float4 f7 = *reinterpret_cast<const float4*>(p7);

    __builtin_amdgcn_sched_barrier(0);   // fence: no consumer hoists above

    // Phase 2: accumulate; coeffs from LDS (broadcast, conflict-free).
    float4 acc = make_float4(0.f, 0.f, 0.f, 0.f);
    #define ACC(FK, K)                                             \
    {                                                              \
        float c = s_c[qbase + K];                                  \
        c = fminf(fmaxf(c, 0.0f), 1.0f);                           \
        acc.x = fmaf(c, FK.x, acc.x);                              \
        acc.y = fmaf(c, FK.y, acc.y);                              \
        acc.z = fmaf(c, FK.z, acc.z);                              \
        acc.w = fmaf(c, FK.w, acc.w);                              \
    }
    ACC(f0, 0) ACC(f1, 1) ACC(f2, 2) ACC(f3, 3)
    ACC(f4, 4) ACC(f5, 5) ACC(f6, 6) ACC(f7, 7)
    #undef ACC

    *reinterpret_cast<float4*>(out + (size_t)n * F + (g << 2)) = acc;
}

extern "C" void kernel_launch(void* const* d_in, const int* in_sizes, int n_in,
                              void* d_out, int out_size, void* d_ws, size_t ws_size,
                              hipStream_t stream) {
    const float* coeffs     = (const float*)d_in[0];   // [N,8] fp32
    const int*   corner_idx = (const int*)d_in[1];     // [N,8] int32
    const float* features   = (const float*)d_in[2];   // [V,32] fp32
    float*       out        = (float*)d_out;           // [N,32] fp32

    const int N = in_sizes[0] / 8;
    const int blocks = (N + QUERIES_PER_BLOCK - 1) / QUERIES_PER_BLOCK;

    SPC_85469849190654_kernel<<<blocks, 256, 0, stream>>>(
        coeffs, corner_idx, features, out, N);
}